// Round 8
// baseline (694.892 us; speedup 1.0000x reference)
//
#include <hip/hip_runtime.h>
#include <hip/hip_bf16.h>

#define N_NODES   100000
#define N_EDGES   3200000
#define F_IN      100
#define H_DIM     64
#define C_NUM     18
#define NPB       1024                      // nodes per csr bucket
#define N_BKT     98                        // ceil(100000/1024)
#define EPB       8192                      // edges per radix block

typedef __attribute__((ext_vector_type(8))) short short8;
typedef __attribute__((ext_vector_type(4))) float f32x4;

// ---- dtype-flexible loads (flags decided at runtime by detect_kernel) ----
__device__ __forceinline__ float ldf(const void* p, long long i, int isbf) {
    if (isbf) return __bfloat162float(((const __hip_bfloat16*)p)[i]);
    return ((const float*)p)[i];
}
__device__ __forceinline__ int ldi(const void* p, long long i, int is64) {
    if (is64) return (int)(((const long long*)p)[i]);
    return ((const int*)p)[i];
}
__device__ __forceinline__ unsigned short f2us(float f) {
    __hip_bfloat16 b = __float2bfloat16(f);
    return *(unsigned short*)&b;
}

// ---- probe input dtypes; write flags ----
__global__ void detect_kernel(const void* ei, const void* x, int* flags)
{
    if (threadIdx.x != 0 || blockIdx.x != 0) return;
    const long long* e64 = (const long long*)ei;
    int ok64 = 1;
    for (int i = 0; i < 128; ++i) {
        long long v = e64[i];
        if (v < 0 || v >= N_NODES) { ok64 = 0; break; }
    }
    const __hip_bfloat16* xb = (const __hip_bfloat16*)x;
    int cnt = 0;
    for (int i = 0; i < 256; ++i) {
        float v = fabsf(__bfloat162float(xb[i]));
        if (v == 0.0f || (v > 9.5367431640625e-7f && v < 1.0e6f)) ++cnt;
    }
    flags[0] = ok64;
    flags[1] = (cnt >= 240) ? 1 : 0;
}

__global__ void zero98(int* __restrict__ pcnt)
{
    int i = threadIdx.x;
    if (i < N_BKT) pcnt[i] = 0;
}

// ---- pass A: bucket histogram, LDS-privatized ----
__global__ __launch_bounds__(1024) void radix_count(const void* ei, int* __restrict__ pcnt,
                                                    const int* __restrict__ flags)
{
    __shared__ int hist[N_BKT];
    const int t = threadIdx.x;
    if (t < N_BKT) hist[t] = 0;
    __syncthreads();
    const int base = blockIdx.x * EPB;
    const int n = min(EPB, N_EDGES - base);
    const int is64 = flags[0];
    for (int j = t; j < n; j += 1024) {
        int d = ldi(ei, (long long)N_EDGES + base + j, is64);
        atomicAdd(&hist[d >> 10], 1);
    }
    __syncthreads();
    if (t < N_BKT) atomicAdd(&pcnt[t], hist[t]);
}

// ---- prefix scan over 98 bucket counts (single block of 128) ----
__global__ void scan98(const int* __restrict__ cnt, int* __restrict__ base,
                       int* __restrict__ cursor)
{
    __shared__ int tmp[128];
    const int t = threadIdx.x;
    int v = (t < N_BKT) ? cnt[t] : 0;
    tmp[t] = v;
    __syncthreads();
    for (int off = 1; off < 128; off <<= 1) {
        int add = (t >= off) ? tmp[t - off] : 0;
        __syncthreads();
        tmp[t] += add;
        __syncthreads();
    }
    if (t < N_BKT) { base[t] = tmp[t] - v; cursor[t] = tmp[t] - v; }
    if (t == 127) base[N_BKT] = tmp[127];   // == N_EDGES
}

// ---- pass B: LDS-staged radix partition into contiguous bucket regions ----
__global__ __launch_bounds__(1024) void radix_scatter(const void* ei, const void* ew,
                                                      int* __restrict__ gcursor,
                                                      uint2* __restrict__ temp,
                                                      const int* __restrict__ flags)
{
    __shared__ uint2 stage[EPB];                  // 64 KB
    __shared__ unsigned char stgb[EPB];           // 8 KB
    __shared__ int hist[128], scan_s[128];
    __shared__ int gbase[N_BKT], lcur[N_BKT];
    const int t = threadIdx.x;
    if (t < 128) hist[t] = 0;
    __syncthreads();

    const int base = blockIdx.x * EPB;
    const int n = min(EPB, N_EDGES - base);
    const int is64 = flags[0], isbf = flags[1];

    int  bkt[8];
    uint2 pk[8];
#pragma unroll
    for (int j = 0; j < 8; ++j) {
        int i = j * 1024 + t;
        bkt[j] = -1;
        if (i < n) {
            int e = base + i;
            int s = ldi(ei, e, is64);
            int d = ldi(ei, (long long)N_EDGES + e, is64);
            float w = ldf(ew, e, isbf);
            bkt[j] = d >> 10;
            pk[j].x = (unsigned)s | ((unsigned)(d & (NPB - 1)) << 17);
            pk[j].y = (unsigned)f2us(w);
            atomicAdd(&hist[bkt[j]], 1);
        }
    }
    __syncthreads();
    if (t < 128) scan_s[t] = hist[t];
    __syncthreads();
    for (int off = 1; off < 128; off <<= 1) {
        int add = 0;
        if (t < 128 && t >= off) add = scan_s[t - off];
        __syncthreads();
        if (t < 128) scan_s[t] += add;
        __syncthreads();
    }
    if (t < N_BKT) {
        int excl = scan_s[t] - hist[t];
        lcur[t] = excl;
        gbase[t] = atomicAdd(&gcursor[t], hist[t]) - excl;
    }
    __syncthreads();
#pragma unroll
    for (int j = 0; j < 8; ++j) {
        if (bkt[j] >= 0) {
            int pos = atomicAdd(&lcur[bkt[j]], 1);
            stage[pos] = pk[j];
            stgb[pos] = (unsigned char)bkt[j];
        }
    }
    __syncthreads();
#pragma unroll
    for (int j = 0; j < 8; ++j) {
        int i = j * 1024 + t;
        if (i < n) {
            int b = stgb[i];
            temp[gbase[b] + i] = stage[i];
        }
    }
}

// ---- pass C: per-bucket CSR finalize (1024 nodes); writes deg/row_start/inv_deg ----
// csr entry: src:17b | bf16-weight-without-sign:15b (weights >= 0)
__global__ __launch_bounds__(1024) void csr_build(const uint2* __restrict__ temp,
                          const int* __restrict__ pbase,
                          unsigned int* __restrict__ csr_pk,
                          int* __restrict__ deg, int* __restrict__ row_start,
                          float* __restrict__ inv_deg)
{
    __shared__ int cnt[NPB], scan_s[NPB], cur[NPB];
    const int b = blockIdx.x;
    const int t = threadIdx.x;
    cnt[t] = 0;
    __syncthreads();
    const int bs = pbase[b];
    const int be = pbase[b + 1];
    for (int i = bs + t; i < be; i += NPB)
        atomicAdd(&cnt[(temp[i].x >> 17) & (NPB - 1)], 1);
    __syncthreads();
    int v = cnt[t];
    scan_s[t] = v;
    __syncthreads();
    for (int off = 1; off < NPB; off <<= 1) {
        int add = (t >= off) ? scan_s[t - off] : 0;
        __syncthreads();
        scan_s[t] += add;
        __syncthreads();
    }
    int excl = bs + scan_s[t] - v;
    cur[t] = excl;
    int node = b * NPB + t;
    if (node < N_NODES) {
        deg[node]       = v;
        row_start[node] = excl;
        inv_deg[node]   = 1.0f / (float)max(v, 1);
    }
    __syncthreads();
    for (int i = bs + t; i < be; i += NPB) {
        uint2 e = temp[i];
        int k = (e.x >> 17) & (NPB - 1);
        int pos = atomicAdd(&cur[k], 1);
        csr_pk[pos] = (e.x & 0x1FFFFu) | ((e.y & 0x7FFFu) << 17);
    }
}

// ---- embedding via MFMA: h = relu(x @ W + b), [64nodes,100pad128] @ [128,64] ----
// staging: coalesced uint2 x-slab copy; b128 conflict-free W writes.
__global__ void embed_mfma(const void* x, const void* W, const void* b,
                           __hip_bfloat16* __restrict__ h, const int* __restrict__ flags)
{
    constexpr int KP = 136;                 // row stride in shorts (272B = 17*16B)
    __shared__ unsigned short W_s[H_DIM * KP];
    __shared__ unsigned short x_s[64 * KP];
    __shared__ float b_s[H_DIM];
    const int t = threadIdx.x;
    const int isbf = flags[1];

    // stage W: thread -> (n = t/16, k8 = t%16), b128 writes (banks 0,4..28 per 8 lanes)
    {
        const int n0 = t >> 4, k8 = t & 15;
        for (int n = n0; n < H_DIM; n += 16) {
            union { unsigned short u[8]; short8 v; } tmp;
#pragma unroll
            for (int j = 0; j < 8; ++j) {
                int k = k8 * 8 + j;
                tmp.u[j] = (k < F_IN) ? f2us(ldf(W, (long long)k * H_DIM + n, isbf))
                                      : (unsigned short)0;
            }
            *(short8*)&W_s[n * KP + k8 * 8] = tmp.v;
        }
    }
    if (t < H_DIM) b_s[t] = ldf(b, t, isbf);

    // stage x slab (64 rows x 100 shorts), coalesced
    const int nb0 = blockIdx.x * 64;
    const int valid = min(64, N_NODES - nb0);
    if (isbf) {
        const uint2* xu = (const uint2*)x + (size_t)nb0 * 25;   // 25 uint2 per row
        for (int i2 = t; i2 < valid * 25; i2 += 256) {
            int row = i2 / 25, col4 = i2 - row * 25;
            *(uint2*)&x_s[row * KP + col4 * 4] = xu[i2];
        }
    } else {
        for (int i = t; i < valid * 100; i += 256) {
            int row = i / 100, col = i - row * 100;
            x_s[row * KP + col] = f2us(((const float*)x)[(size_t)(nb0 + row) * 100 + col]);
        }
    }
    for (int i = t; i < 64 * 32; i += 256) {           // zero pad cols 100..131
        int row = i >> 5, col = 100 + (i & 31);
        x_s[row * KP + col] = 0;
    }
    if (valid < 64) {                                   // zero invalid rows
        for (int i = t; i < (64 - valid) * 100; i += 256) {
            int row = valid + i / 100, col = i % 100;
            x_s[row * KP + col] = 0;
        }
    }
    __syncthreads();

    const int wave = t >> 6, lane = t & 63, c = lane & 15, quad = lane >> 4;
    short8 bfrag[4][4];
#pragma unroll
    for (int nt = 0; nt < 4; ++nt)
#pragma unroll
        for (int kt = 0; kt < 4; ++kt)
            bfrag[nt][kt] = *(const short8*)&W_s[(nt * 16 + c) * KP + kt * 32 + quad * 8];

    short8 afrag[4];
#pragma unroll
    for (int kt = 0; kt < 4; ++kt)
        afrag[kt] = *(const short8*)&x_s[(wave * 16 + c) * KP + kt * 32 + quad * 8];

    f32x4 acc[4] = {};
#pragma unroll
    for (int nt = 0; nt < 4; ++nt)
#pragma unroll
        for (int kt = 0; kt < 4; ++kt)
            acc[nt] = __builtin_amdgcn_mfma_f32_16x16x32_bf16(afrag[kt], bfrag[nt][kt], acc[nt], 0, 0, 0);

    const int nb = nb0 + wave * 16;
#pragma unroll
    for (int nt = 0; nt < 4; ++nt)
#pragma unroll
        for (int reg = 0; reg < 4; ++reg) {
            int nn = nb + quad * 4 + reg;
            int col = nt * 16 + c;
            if (nn < N_NODES) {
                float v = fmaxf(acc[nt][reg] + b_s[col], 0.0f);
                h[(size_t)nn * H_DIM + col] = __float2bfloat16(v);
            }
        }
}

// ---- fused SAGE layer: gather means to LDS, then MFMA transform ----
// block = 64 nodes (4 waves x 16); out buffer != in buffer (no aliasing).
template <int COUT, bool RELU, bool USE_W, bool FINAL>
__global__ void sage_fused(const __hip_bfloat16* __restrict__ h_in,
                           const unsigned int* __restrict__ csr_pk,
                           const int* __restrict__ row_start,
                           const int* __restrict__ deg,
                           const float* __restrict__ inv_deg,
                           const void* Wl, const void* bl, const void* Wr,
                           __hip_bfloat16* __restrict__ h_out,
                           const int* __restrict__ flags, void* dout)
{
    constexpr int CP = (COUT + 15) & ~15;   // 64 or 32
    constexpr int NT = CP / 16;
    constexpr int KP = 136;                 // W row stride (shorts)
    constexpr int MP = 72;                  // mean row stride (shorts)
    __shared__ unsigned short W_s[CP * KP];
    __shared__ unsigned short mean_s[64 * MP];
    __shared__ float b_s[CP];
    const int t = threadIdx.x;
    const int isbf = flags[1];

    // stage W = [Wl;Wr] (128 x COUT), b128 conflict-free writes
    {
        const int n0 = t >> 4, k8 = t & 15;
        for (int n = n0; n < CP; n += 16) {
            union { unsigned short u[8]; short8 v; } tmp;
#pragma unroll
            for (int j = 0; j < 8; ++j) {
                int k = k8 * 8 + j;
                float v = 0.0f;
                if (n < COUT)
                    v = (k < 64) ? ldf(Wl, (long long)k * COUT + n, isbf)
                                 : ldf(Wr, (long long)(k - 64) * COUT + n, isbf);
                tmp.u[j] = f2us(v);
            }
            *(short8*)&W_s[n * KP + k8 * 8] = tmp.v;
        }
    }
    if (t < CP) b_s[t] = (t < COUT) ? ldf(bl, t, isbf) : 0.0f;

    const int wave = t >> 6, lane = t & 63;
    const int c8 = lane & 7;     // feature oct (8 x 8 features)
    const int r  = lane >> 3;    // neighbor sub-index (8)
    const int nb = blockIdx.x * 64;

    // ---- phase A: gather means for this wave's 16 nodes into LDS ----
    for (int i = 0; i < 16; ++i) {
        const int row = wave * 16 + i;
        const int n = nb + row;
        if (n >= N_NODES) {
            if (r == 0) { short8 z = {}; *(short8*)&mean_s[row * MP + c8 * 8] = z; }
            continue;
        }
        const int start = row_start[n];
        const int d     = deg[n];
        unsigned int ev = 0;
        if (lane < d) ev = csr_pk[start + lane];
        const int dmain = min(d, 64);
        float a0 = 0.f, a1 = 0.f, a2 = 0.f, a3 = 0.f;
        float a4 = 0.f, a5 = 0.f, a6 = 0.f, a7 = 0.f;
#pragma unroll 2
        for (int j0 = 0; j0 < dmain; j0 += 8) {
            unsigned int e = __shfl(ev, j0 + r);
            int s = e & 0x1FFFF;                 // invalid lanes: ev=0 -> s=0, w=0
            float w;
            if (USE_W) w = __uint_as_float((e & 0xFFFE0000u) >> 1);
            else       w = (j0 + r < dmain) ? 1.0f : 0.0f;
            uint4 hv = *(const uint4*)(h_in + (size_t)s * H_DIM + 8 * c8);
            a0 = fmaf(w, __uint_as_float(hv.x << 16),          a0);
            a1 = fmaf(w, __uint_as_float(hv.x & 0xFFFF0000u),  a1);
            a2 = fmaf(w, __uint_as_float(hv.y << 16),          a2);
            a3 = fmaf(w, __uint_as_float(hv.y & 0xFFFF0000u),  a3);
            a4 = fmaf(w, __uint_as_float(hv.z << 16),          a4);
            a5 = fmaf(w, __uint_as_float(hv.z & 0xFFFF0000u),  a5);
            a6 = fmaf(w, __uint_as_float(hv.w << 16),          a6);
            a7 = fmaf(w, __uint_as_float(hv.w & 0xFFFF0000u),  a7);
        }
        for (int j = 64 + r; j < d; j += 8) {    // rare tail deg>64
            unsigned int e = csr_pk[start + j];
            int s = e & 0x1FFFF;
            float w = USE_W ? __uint_as_float((e & 0xFFFE0000u) >> 1) : 1.0f;
            uint4 hv = *(const uint4*)(h_in + (size_t)s * H_DIM + 8 * c8);
            a0 = fmaf(w, __uint_as_float(hv.x << 16),          a0);
            a1 = fmaf(w, __uint_as_float(hv.x & 0xFFFF0000u),  a1);
            a2 = fmaf(w, __uint_as_float(hv.y << 16),          a2);
            a3 = fmaf(w, __uint_as_float(hv.y & 0xFFFF0000u),  a3);
            a4 = fmaf(w, __uint_as_float(hv.z << 16),          a4);
            a5 = fmaf(w, __uint_as_float(hv.z & 0xFFFF0000u),  a5);
            a6 = fmaf(w, __uint_as_float(hv.w << 16),          a6);
            a7 = fmaf(w, __uint_as_float(hv.w & 0xFFFF0000u),  a7);
        }
#pragma unroll
        for (int m = 8; m <= 32; m <<= 1) {
            a0 += __shfl_xor(a0, m); a1 += __shfl_xor(a1, m);
            a2 += __shfl_xor(a2, m); a3 += __shfl_xor(a3, m);
            a4 += __shfl_xor(a4, m); a5 += __shfl_xor(a5, m);
            a6 += __shfl_xor(a6, m); a7 += __shfl_xor(a7, m);
        }
        if (r == 0) {
            float inv = inv_deg[n];
            union { unsigned short u[8]; short8 v; } st;
            st.u[0] = f2us(a0 * inv); st.u[1] = f2us(a1 * inv);
            st.u[2] = f2us(a2 * inv); st.u[3] = f2us(a3 * inv);
            st.u[4] = f2us(a4 * inv); st.u[5] = f2us(a5 * inv);
            st.u[6] = f2us(a6 * inv); st.u[7] = f2us(a7 * inv);
            *(short8*)&mean_s[row * MP + c8 * 8] = st.v;
        }
    }
    __syncthreads();

    // ---- phase B: MFMA transform out = L2norm([mean|h] @ W + b) ----
    const int c = lane & 15, quad = lane >> 4;
    short8 bfrag[NT][4];
#pragma unroll
    for (int nt = 0; nt < NT; ++nt)
#pragma unroll
        for (int kt = 0; kt < 4; ++kt)
            bfrag[nt][kt] = *(const short8*)&W_s[(nt * 16 + c) * KP + kt * 32 + quad * 8];

    const int nbw = nb + wave * 16;
    int node = nbw + c; if (node >= N_NODES) node = N_NODES - 1;

    short8 afrag[4];
#pragma unroll
    for (int kt = 0; kt < 4; ++kt) {
        if (kt < 2)
            afrag[kt] = *(const short8*)&mean_s[(wave * 16 + c) * MP + kt * 32 + quad * 8];
        else
            afrag[kt] = *(const short8*)(h_in + (size_t)node * H_DIM + (kt - 2) * 32 + quad * 8);
    }

    f32x4 acc[NT] = {};
#pragma unroll
    for (int nt = 0; nt < NT; ++nt)
#pragma unroll
        for (int kt = 0; kt < 4; ++kt)
            acc[nt] = __builtin_amdgcn_mfma_f32_16x16x32_bf16(afrag[kt], bfrag[nt][kt], acc[nt], 0, 0, 0);

    float rs[4];
#pragma unroll
    for (int reg = 0; reg < 4; ++reg) {
        float s2 = 0.f;
#pragma unroll
        for (int nt = 0; nt < NT; ++nt) {
            float v = acc[nt][reg] + b_s[nt * 16 + c];
            acc[nt][reg] = v;
            s2 += v * v;
        }
        s2 += __shfl_xor(s2, 1); s2 += __shfl_xor(s2, 2);
        s2 += __shfl_xor(s2, 4); s2 += __shfl_xor(s2, 8);
        rs[reg] = 1.0f / fmaxf(sqrtf(s2), 1e-12f);
    }

#pragma unroll
    for (int nt = 0; nt < NT; ++nt)
#pragma unroll
        for (int reg = 0; reg < 4; ++reg) {
            int nn  = nbw + quad * 4 + reg;
            int col = nt * 16 + c;
            if (nn < N_NODES && col < COUT) {
                float v = acc[nt][reg] * rs[reg];
                if (RELU) v = fmaxf(v, 0.0f);
                if (FINAL) {
                    if (isbf) ((__hip_bfloat16*)dout)[(size_t)nn * COUT + col] = __float2bfloat16(v);
                    else      ((float*)dout)[(size_t)nn * COUT + col] = v;
                } else {
                    h_out[(size_t)nn * H_DIM + col] = __float2bfloat16(v);
                }
            }
        }
}

extern "C" void kernel_launch(void* const* d_in, const int* in_sizes, int n_in,
                              void* d_out, int out_size, void* d_ws, size_t ws_size,
                              hipStream_t stream)
{
    const void* x    = d_in[0];
    const void* ei   = d_in[1];
    const void* ew   = d_in[2];
    const void* embW = d_in[3];
    const void* embB = d_in[4];
    const void* Wl1 = d_in[5];  const void* bl1 = d_in[6];  const void* Wr1 = d_in[7];
    const void* Wl2 = d_in[8];  const void* bl2 = d_in[9];  const void* Wr2 = d_in[10];
    const void* Wl3 = d_in[11]; const void* bl3 = d_in[12]; const void* Wr3 = d_in[13];
    const void* Wl4 = d_in[14]; const void* bl4 = d_in[15]; const void* Wr4 = d_in[16];
    (void)in_sizes; (void)n_in; (void)out_size; (void)ws_size;

    char* ws = (char*)d_ws;
    size_t off = 0;
    auto alloc = [&](size_t bytes) -> void* {
        void* p = ws + off;
        off += (bytes + 255) & ~(size_t)255;
        return p;
    };
    // temp (edge staging, 25.6 MB) is dead after csr_build; hA/hB alias it.
    uint2* temp = (uint2*)alloc((size_t)N_EDGES * sizeof(uint2));
    __hip_bfloat16* hA = (__hip_bfloat16*)temp;
    __hip_bfloat16* hB = (__hip_bfloat16*)((char*)temp + (size_t)N_NODES * H_DIM * 2);
    unsigned int* csr_pk = (unsigned int*)alloc((size_t)N_EDGES * sizeof(unsigned int));
    int*   pcnt    = (int*)  alloc((N_BKT)     * sizeof(int));
    int*   pbase   = (int*)  alloc((N_BKT + 1) * sizeof(int));
    int*   pcursor = (int*)  alloc((N_BKT)     * sizeof(int));
    int*   deg     = (int*)  alloc((size_t)N_NODES * sizeof(int));
    int*   row_st  = (int*)  alloc((size_t)N_NODES * sizeof(int));
    float* inv_deg = (float*)alloc((size_t)N_NODES * sizeof(float));
    int*   flags   = (int*)  alloc(256);

    const int NBr = (N_EDGES + EPB - 1) / EPB;   // 391 radix blocks
    const int NBt = (N_NODES + 63) / 64;         // 1563 blocks of 64 nodes

    detect_kernel<<<1, 64, 0, stream>>>(ei, x, flags);
    zero98<<<1, 128, 0, stream>>>(pcnt);
    radix_count<<<NBr, 1024, 0, stream>>>(ei, pcnt, flags);
    scan98<<<1, 128, 0, stream>>>(pcnt, pbase, pcursor);
    radix_scatter<<<NBr, 1024, 0, stream>>>(ei, ew, pcursor, temp, flags);
    csr_build<<<N_BKT, NPB, 0, stream>>>(temp, pbase, csr_pk, deg, row_st, inv_deg);

    embed_mfma<<<NBt, 256, 0, stream>>>(x, embW, embB, hA, flags);

    sage_fused<H_DIM, true,  true,  false><<<NBt, 256, 0, stream>>>(
        hA, csr_pk, row_st, deg, inv_deg, Wl1, bl1, Wr1, hB, flags, d_out);
    sage_fused<H_DIM, true,  true,  false><<<NBt, 256, 0, stream>>>(
        hB, csr_pk, row_st, deg, inv_deg, Wl2, bl2, Wr2, hA, flags, d_out);
    sage_fused<H_DIM, true,  true,  false><<<NBt, 256, 0, stream>>>(
        hA, csr_pk, row_st, deg, inv_deg, Wl3, bl3, Wr3, hB, flags, d_out);
    sage_fused<C_NUM, false, false, true ><<<NBt, 256, 0, stream>>>(
        hB, csr_pk, row_st, deg, inv_deg, Wl4, bl4, Wr4, nullptr, flags, d_out);
}

// Round 9
// 529.696 us; speedup vs baseline: 1.3119x; 1.3119x over previous
//
#include <hip/hip_runtime.h>
#include <hip/hip_bf16.h>

#define N_NODES   100000
#define N_EDGES   3200000
#define F_IN      100
#define H_DIM     64
#define C_NUM     18
#define NPB       1024                      // nodes per csr bucket
#define N_BKT     98                        // ceil(100000/1024)
#define EPB       8192                      // edges per radix block
#define N_TILES   1563                      // ceil(100000/64)

typedef __attribute__((ext_vector_type(8))) short short8;
typedef __attribute__((ext_vector_type(4))) float f32x4;

// ---- dtype-flexible loads (flags decided at runtime by detect_kernel) ----
__device__ __forceinline__ float ldf(const void* p, long long i, int isbf) {
    if (isbf) return __bfloat162float(((const __hip_bfloat16*)p)[i]);
    return ((const float*)p)[i];
}
__device__ __forceinline__ int ldi(const void* p, long long i, int is64) {
    if (is64) return (int)(((const long long*)p)[i]);
    return ((const int*)p)[i];
}
__device__ __forceinline__ unsigned short f2us(float f) {
    __hip_bfloat16 b = __float2bfloat16(f);
    return *(unsigned short*)&b;
}

// ---- probe input dtypes; write flags ----
__global__ void detect_kernel(const void* ei, const void* x, int* flags)
{
    if (threadIdx.x != 0 || blockIdx.x != 0) return;
    const long long* e64 = (const long long*)ei;
    int ok64 = 1;
    for (int i = 0; i < 128; ++i) {
        long long v = e64[i];
        if (v < 0 || v >= N_NODES) { ok64 = 0; break; }
    }
    const __hip_bfloat16* xb = (const __hip_bfloat16*)x;
    int cnt = 0;
    for (int i = 0; i < 256; ++i) {
        float v = fabsf(__bfloat162float(xb[i]));
        if (v == 0.0f || (v > 9.5367431640625e-7f && v < 1.0e6f)) ++cnt;
    }
    flags[0] = ok64;
    flags[1] = (cnt >= 240) ? 1 : 0;
}

__global__ void zero98(int* __restrict__ pcnt)
{
    int i = threadIdx.x;
    if (i < N_BKT) pcnt[i] = 0;
}

// ---- pass A: bucket histogram, LDS-privatized ----
__global__ __launch_bounds__(1024) void radix_count(const void* ei, int* __restrict__ pcnt,
                                                    const int* __restrict__ flags)
{
    __shared__ int hist[N_BKT];
    const int t = threadIdx.x;
    if (t < N_BKT) hist[t] = 0;
    __syncthreads();
    const int base = blockIdx.x * EPB;
    const int n = min(EPB, N_EDGES - base);
    const int is64 = flags[0];
    for (int j = t; j < n; j += 1024) {
        int d = ldi(ei, (long long)N_EDGES + base + j, is64);
        atomicAdd(&hist[d >> 10], 1);
    }
    __syncthreads();
    if (t < N_BKT) atomicAdd(&pcnt[t], hist[t]);
}

// ---- prefix scan over 98 bucket counts (single block of 128) ----
__global__ void scan98(const int* __restrict__ cnt, int* __restrict__ base,
                       int* __restrict__ cursor)
{
    __shared__ int tmp[128];
    const int t = threadIdx.x;
    int v = (t < N_BKT) ? cnt[t] : 0;
    tmp[t] = v;
    __syncthreads();
    for (int off = 1; off < 128; off <<= 1) {
        int add = (t >= off) ? tmp[t - off] : 0;
        __syncthreads();
        tmp[t] += add;
        __syncthreads();
    }
    if (t < N_BKT) { base[t] = tmp[t] - v; cursor[t] = tmp[t] - v; }
    if (t == 127) base[N_BKT] = tmp[127];   // == N_EDGES
}

// ---- pass B: LDS-staged radix partition into contiguous bucket regions ----
__global__ __launch_bounds__(1024) void radix_scatter(const void* ei, const void* ew,
                                                      int* __restrict__ gcursor,
                                                      uint2* __restrict__ temp,
                                                      const int* __restrict__ flags)
{
    __shared__ uint2 stage[EPB];                  // 64 KB
    __shared__ unsigned char stgb[EPB];           // 8 KB
    __shared__ int hist[128], scan_s[128];
    __shared__ int gbase[N_BKT], lcur[N_BKT];
    const int t = threadIdx.x;
    if (t < 128) hist[t] = 0;
    __syncthreads();

    const int base = blockIdx.x * EPB;
    const int n = min(EPB, N_EDGES - base);
    const int is64 = flags[0], isbf = flags[1];

    int  bkt[8];
    uint2 pk[8];
#pragma unroll
    for (int j = 0; j < 8; ++j) {
        int i = j * 1024 + t;
        bkt[j] = -1;
        if (i < n) {
            int e = base + i;
            int s = ldi(ei, e, is64);
            int d = ldi(ei, (long long)N_EDGES + e, is64);
            float w = ldf(ew, e, isbf);
            bkt[j] = d >> 10;
            pk[j].x = (unsigned)s | ((unsigned)(d & (NPB - 1)) << 17);
            pk[j].y = (unsigned)f2us(w);
            atomicAdd(&hist[bkt[j]], 1);
        }
    }
    __syncthreads();
    if (t < 128) scan_s[t] = hist[t];
    __syncthreads();
    for (int off = 1; off < 128; off <<= 1) {
        int add = 0;
        if (t < 128 && t >= off) add = scan_s[t - off];
        __syncthreads();
        if (t < 128) scan_s[t] += add;
        __syncthreads();
    }
    if (t < N_BKT) {
        int excl = scan_s[t] - hist[t];
        lcur[t] = excl;
        gbase[t] = atomicAdd(&gcursor[t], hist[t]) - excl;
    }
    __syncthreads();
#pragma unroll
    for (int j = 0; j < 8; ++j) {
        if (bkt[j] >= 0) {
            int pos = atomicAdd(&lcur[bkt[j]], 1);
            stage[pos] = pk[j];
            stgb[pos] = (unsigned char)bkt[j];
        }
    }
    __syncthreads();
#pragma unroll
    for (int j = 0; j < 8; ++j) {
        int i = j * 1024 + t;
        if (i < n) {
            int b = stgb[i];
            temp[gbase[b] + i] = stage[i];
        }
    }
}

// ---- pass C: per-bucket CSR finalize (1024 nodes); writes deg/row_start/inv_deg ----
// csr entry: src:17b | bf16-weight-without-sign:15b (weights >= 0)
__global__ __launch_bounds__(1024) void csr_build(const uint2* __restrict__ temp,
                          const int* __restrict__ pbase,
                          unsigned int* __restrict__ csr_pk,
                          int* __restrict__ deg, int* __restrict__ row_start,
                          float* __restrict__ inv_deg)
{
    __shared__ int cnt[NPB], scan_s[NPB], cur[NPB];
    const int b = blockIdx.x;
    const int t = threadIdx.x;
    cnt[t] = 0;
    __syncthreads();
    const int bs = pbase[b];
    const int be = pbase[b + 1];
    for (int i = bs + t; i < be; i += NPB)
        atomicAdd(&cnt[(temp[i].x >> 17) & (NPB - 1)], 1);
    __syncthreads();
    int v = cnt[t];
    scan_s[t] = v;
    __syncthreads();
    for (int off = 1; off < NPB; off <<= 1) {
        int add = (t >= off) ? scan_s[t - off] : 0;
        __syncthreads();
        scan_s[t] += add;
        __syncthreads();
    }
    int excl = bs + scan_s[t] - v;
    cur[t] = excl;
    int node = b * NPB + t;
    if (node < N_NODES) {
        deg[node]       = v;
        row_start[node] = excl;
        inv_deg[node]   = 1.0f / (float)max(v, 1);
    }
    __syncthreads();
    for (int i = bs + t; i < be; i += NPB) {
        uint2 e = temp[i];
        int k = (e.x >> 17) & (NPB - 1);
        int pos = atomicAdd(&cur[k], 1);
        csr_pk[pos] = (e.x & 0x1FFFFu) | ((e.y & 0x7FFFu) << 17);
    }
}

// conflict-free W staging into W_s[n*KP + k] (KP=136): lane group n=t>>3, k8=t&7
// slot (17n+k8) mod 8 distinct within each 8-lane group -> no bank conflicts.
template <int CP, int COUT>
__device__ __forceinline__ void stage_W(unsigned short* W_s, const void* Wl, const void* Wr,
                                        int t, int isbf)
{
    constexpr int KP = 136;
    const int n0 = t >> 3, k8a = t & 7;
    for (int n = n0; n < CP; n += 32) {
#pragma unroll
        for (int hh = 0; hh < 2; ++hh) {
            int k8 = k8a + hh * 8;
            union { unsigned short u[8]; short8 v; } tmp;
#pragma unroll
            for (int j = 0; j < 8; ++j) {
                int k = k8 * 8 + j;
                float val = 0.0f;
                if (n < COUT && k < 128)
                    val = (k < 64) ? ldf(Wl, (long long)k * COUT + n, isbf)
                                   : ldf(Wr, (long long)(k - 64) * COUT + n, isbf);
                tmp.u[j] = f2us(val);
            }
            *(short8*)&W_s[n * KP + k8 * 8] = tmp.v;
        }
    }
}

// ---- embedding via MFMA: h = relu(x @ W + b); grid-stride over 64-node tiles ----
__global__ void embed_mfma(const void* x, const void* W, const void* b,
                           __hip_bfloat16* __restrict__ h, const int* __restrict__ flags)
{
    constexpr int KP = 136;
    __shared__ unsigned short W_s[H_DIM * KP];
    __shared__ unsigned short x_s[64 * KP];
    __shared__ float b_s[H_DIM];
    const int t = threadIdx.x;
    const int isbf = flags[1];

    // stage W (transposed, conflict-free). W is [k][n] with n fast, COUT=H_DIM.
    {
        const int n0 = t >> 3, k8a = t & 7;
        for (int n = n0; n < H_DIM; n += 32) {
#pragma unroll
            for (int hh = 0; hh < 2; ++hh) {
                int k8 = k8a + hh * 8;
                union { unsigned short u[8]; short8 v; } tmp;
#pragma unroll
                for (int j = 0; j < 8; ++j) {
                    int k = k8 * 8 + j;
                    tmp.u[j] = (k < F_IN) ? f2us(ldf(W, (long long)k * H_DIM + n, isbf))
                                          : (unsigned short)0;
                }
                *(short8*)&W_s[n * KP + k8 * 8] = tmp.v;
            }
        }
    }
    if (t < H_DIM) b_s[t] = ldf(b, t, isbf);
    // zero x_s pad cols 100..135 once (rewritten cols 0..99 each tile)
    for (int i = t; i < 64 * 36; i += 256) {
        int row = i / 36, col = 100 + (i % 36);
        x_s[row * KP + col] = 0;
    }

    const int wave = t >> 6, lane = t & 63, c = lane & 15, quad = lane >> 4;

    for (int tile = blockIdx.x; tile < N_TILES; tile += gridDim.x) {
        const int nb0 = tile * 64;
        const int valid = min(64, N_NODES - nb0);
        __syncthreads();   // prior tile's reads done
        if (isbf) {
            const uint2* xu = (const uint2*)x + (size_t)nb0 * 25;   // 25 uint2 per row
            for (int i2 = t; i2 < valid * 25; i2 += 256) {
                int row = i2 / 25, col4 = i2 - row * 25;
                *(uint2*)&x_s[row * KP + col4 * 4] = xu[i2];
            }
        } else {
            for (int i = t; i < valid * 100; i += 256) {
                int row = i / 100, col = i - row * 100;
                x_s[row * KP + col] = f2us(((const float*)x)[(size_t)(nb0 + row) * 100 + col]);
            }
        }
        if (valid < 64) {
            for (int i = t; i < (64 - valid) * 100; i += 256) {
                int row = valid + i / 100, col = i % 100;
                x_s[row * KP + col] = 0;
            }
        }
        __syncthreads();

        short8 bfrag[4][4];
#pragma unroll
        for (int nt = 0; nt < 4; ++nt)
#pragma unroll
            for (int kt = 0; kt < 4; ++kt)
                bfrag[nt][kt] = *(const short8*)&W_s[(nt * 16 + c) * KP + kt * 32 + quad * 8];

        short8 afrag[4];
#pragma unroll
        for (int kt = 0; kt < 4; ++kt)
            afrag[kt] = *(const short8*)&x_s[(wave * 16 + c) * KP + kt * 32 + quad * 8];

        f32x4 acc[4] = {};
#pragma unroll
        for (int nt = 0; nt < 4; ++nt)
#pragma unroll
            for (int kt = 0; kt < 4; ++kt)
                acc[nt] = __builtin_amdgcn_mfma_f32_16x16x32_bf16(afrag[kt], bfrag[nt][kt], acc[nt], 0, 0, 0);

        const int nb = nb0 + wave * 16;
#pragma unroll
        for (int nt = 0; nt < 4; ++nt)
#pragma unroll
            for (int reg = 0; reg < 4; ++reg) {
                int nn = nb + quad * 4 + reg;
                int col = nt * 16 + c;
                if (nn < N_NODES) {
                    float v = fmaxf(acc[nt][reg] + b_s[col], 0.0f);
                    h[(size_t)nn * H_DIM + col] = __float2bfloat16(v);
                }
            }
    }
}

// ---- gather: mean[n] = inv_deg * sum_j w_j * h[src_j]; 2 nodes per wave ----
// lane = (r,c8): r = neighbor sub (8), c8 = feature oct (8 x 8 features, 16B loads)
template <bool USE_W>
__global__ void gather_mean(const __hip_bfloat16* __restrict__ h,
                            const unsigned int* __restrict__ csr_pk,
                            const int* __restrict__ row_start,
                            const int* __restrict__ deg,
                            const float* __restrict__ inv_deg,
                            __hip_bfloat16* __restrict__ mean)
{
    const int lane = threadIdx.x & 63;
    const int c8 = lane & 7;
    const int r  = lane >> 3;
    const int wid = blockIdx.x * 4 + (threadIdx.x >> 6);
    const int nw  = gridDim.x * 4;
    const int NP  = N_NODES / 2;   // 50000 pairs

    for (int p = wid; p < NP; p += nw) {
        const int n0 = 2 * p, n1 = 2 * p + 1;
        const int s0 = row_start[n0], d0 = deg[n0];
        const int s1 = row_start[n1], d1 = deg[n1];
        unsigned int ev0 = (lane < d0) ? csr_pk[s0 + lane] : 0u;
        unsigned int ev1 = (lane < d1) ? csr_pk[s1 + lane] : 0u;
        const int m0 = min(d0, 64), m1 = min(d1, 64);
        const int mm = max(m0, m1);
        float a0[8] = {}, a1[8] = {};
        for (int j0 = 0; j0 < mm; j0 += 8) {
            unsigned int e0 = __shfl(ev0, j0 + r);
            unsigned int e1 = __shfl(ev1, j0 + r);
            float w0, w1;
            if (USE_W) {
                w0 = __uint_as_float((e0 & 0xFFFE0000u) >> 1);   // ev=0 -> w=0
                w1 = __uint_as_float((e1 & 0xFFFE0000u) >> 1);
            } else {
                w0 = (j0 + r < m0) ? 1.0f : 0.0f;
                w1 = (j0 + r < m1) ? 1.0f : 0.0f;
            }
            // issue both independent loads before the fma chains
            uint4 hv0 = *(const uint4*)(h + (size_t)(e0 & 0x1FFFF) * H_DIM + 8 * c8);
            uint4 hv1 = *(const uint4*)(h + (size_t)(e1 & 0x1FFFF) * H_DIM + 8 * c8);
            a0[0] = fmaf(w0, __uint_as_float(hv0.x << 16),         a0[0]);
            a0[1] = fmaf(w0, __uint_as_float(hv0.x & 0xFFFF0000u), a0[1]);
            a0[2] = fmaf(w0, __uint_as_float(hv0.y << 16),         a0[2]);
            a0[3] = fmaf(w0, __uint_as_float(hv0.y & 0xFFFF0000u), a0[3]);
            a0[4] = fmaf(w0, __uint_as_float(hv0.z << 16),         a0[4]);
            a0[5] = fmaf(w0, __uint_as_float(hv0.z & 0xFFFF0000u), a0[5]);
            a0[6] = fmaf(w0, __uint_as_float(hv0.w << 16),         a0[6]);
            a0[7] = fmaf(w0, __uint_as_float(hv0.w & 0xFFFF0000u), a0[7]);
            a1[0] = fmaf(w1, __uint_as_float(hv1.x << 16),         a1[0]);
            a1[1] = fmaf(w1, __uint_as_float(hv1.x & 0xFFFF0000u), a1[1]);
            a1[2] = fmaf(w1, __uint_as_float(hv1.y << 16),         a1[2]);
            a1[3] = fmaf(w1, __uint_as_float(hv1.y & 0xFFFF0000u), a1[3]);
            a1[4] = fmaf(w1, __uint_as_float(hv1.z << 16),         a1[4]);
            a1[5] = fmaf(w1, __uint_as_float(hv1.z & 0xFFFF0000u), a1[5]);
            a1[6] = fmaf(w1, __uint_as_float(hv1.w << 16),         a1[6]);
            a1[7] = fmaf(w1, __uint_as_float(hv1.w & 0xFFFF0000u), a1[7]);
        }
        // rare tails (deg > 64)
        for (int j = 64 + r; j < d0; j += 8) {
            unsigned int e = csr_pk[s0 + j];
            float w = USE_W ? __uint_as_float((e & 0xFFFE0000u) >> 1) : 1.0f;
            uint4 hv = *(const uint4*)(h + (size_t)(e & 0x1FFFF) * H_DIM + 8 * c8);
            a0[0] = fmaf(w, __uint_as_float(hv.x << 16),         a0[0]);
            a0[1] = fmaf(w, __uint_as_float(hv.x & 0xFFFF0000u), a0[1]);
            a0[2] = fmaf(w, __uint_as_float(hv.y << 16),         a0[2]);
            a0[3] = fmaf(w, __uint_as_float(hv.y & 0xFFFF0000u), a0[3]);
            a0[4] = fmaf(w, __uint_as_float(hv.z << 16),         a0[4]);
            a0[5] = fmaf(w, __uint_as_float(hv.z & 0xFFFF0000u), a0[5]);
            a0[6] = fmaf(w, __uint_as_float(hv.w << 16),         a0[6]);
            a0[7] = fmaf(w, __uint_as_float(hv.w & 0xFFFF0000u), a0[7]);
        }
        for (int j = 64 + r; j < d1; j += 8) {
            unsigned int e = csr_pk[s1 + j];
            float w = USE_W ? __uint_as_float((e & 0xFFFE0000u) >> 1) : 1.0f;
            uint4 hv = *(const uint4*)(h + (size_t)(e & 0x1FFFF) * H_DIM + 8 * c8);
            a1[0] = fmaf(w, __uint_as_float(hv.x << 16),         a1[0]);
            a1[1] = fmaf(w, __uint_as_float(hv.x & 0xFFFF0000u), a1[1]);
            a1[2] = fmaf(w, __uint_as_float(hv.y << 16),         a1[2]);
            a1[3] = fmaf(w, __uint_as_float(hv.y & 0xFFFF0000u), a1[3]);
            a1[4] = fmaf(w, __uint_as_float(hv.z << 16),         a1[4]);
            a1[5] = fmaf(w, __uint_as_float(hv.z & 0xFFFF0000u), a1[5]);
            a1[6] = fmaf(w, __uint_as_float(hv.w << 16),         a1[6]);
            a1[7] = fmaf(w, __uint_as_float(hv.w & 0xFFFF0000u), a1[7]);
        }
#pragma unroll
        for (int m = 8; m <= 32; m <<= 1) {
#pragma unroll
            for (int q = 0; q < 8; ++q) {
                a0[q] += __shfl_xor(a0[q], m);
                a1[q] += __shfl_xor(a1[q], m);
            }
        }
        if (r == 0) {
            float inv = inv_deg[n0];
            union { unsigned short u[8]; short8 v; } st;
#pragma unroll
            for (int q = 0; q < 8; ++q) st.u[q] = f2us(a0[q] * inv);
            *(short8*)(mean + (size_t)n0 * H_DIM + 8 * c8) = st.v;
        } else if (r == 1) {
            float inv = inv_deg[n1];
            union { unsigned short u[8]; short8 v; } st;
#pragma unroll
            for (int q = 0; q < 8; ++q) st.u[q] = f2us(a1[q] * inv);
            *(short8*)(mean + (size_t)n1 * H_DIM + 8 * c8) = st.v;
        }
    }
}

// ---- transform via MFMA: out = L2norm([mean|h] @ [Wl;Wr] + b); grid-stride tiles ----
template <int COUT, bool RELU, bool FINAL>
__global__ void transform_mfma(const __hip_bfloat16* __restrict__ meanp,
                               const __hip_bfloat16* __restrict__ hp,
                               const void* Wl, const void* bl, const void* Wr,
                               __hip_bfloat16* __restrict__ h_out,
                               const int* __restrict__ flags, void* dout)
{
    constexpr int CP = (COUT + 15) & ~15;   // 64 or 32
    constexpr int NT = CP / 16;
    constexpr int KP = 136;
    __shared__ unsigned short W_s[CP * KP];
    __shared__ float b_s[CP];
    const int t = threadIdx.x;
    const int isbf = flags[1];
    stage_W<CP, COUT>(W_s, Wl, Wr, t, isbf);
    if (t < CP) b_s[t] = (t < COUT) ? ldf(bl, t, isbf) : 0.0f;
    __syncthreads();

    const int wave = t >> 6, lane = t & 63, c = lane & 15, quad = lane >> 4;
    short8 bfrag[NT][4];
#pragma unroll
    for (int nt = 0; nt < NT; ++nt)
#pragma unroll
        for (int kt = 0; kt < 4; ++kt)
            bfrag[nt][kt] = *(const short8*)&W_s[(nt * 16 + c) * KP + kt * 32 + quad * 8];

    for (int tile = blockIdx.x; tile < N_TILES; tile += gridDim.x) {
        const int nbw = tile * 64 + wave * 16;
        if (nbw >= N_NODES) continue;
        int node = nbw + c; if (node >= N_NODES) node = N_NODES - 1;

        short8 afrag[4];
#pragma unroll
        for (int kt = 0; kt < 4; ++kt) {
            const __hip_bfloat16* sp = (kt < 2) ? meanp : hp;
            afrag[kt] = *(const short8*)(sp + (size_t)node * H_DIM + (kt & 1) * 32 + quad * 8);
        }

        f32x4 acc[NT] = {};
#pragma unroll
        for (int nt = 0; nt < NT; ++nt)
#pragma unroll
            for (int kt = 0; kt < 4; ++kt)
                acc[nt] = __builtin_amdgcn_mfma_f32_16x16x32_bf16(afrag[kt], bfrag[nt][kt], acc[nt], 0, 0, 0);

        float rs[4];
#pragma unroll
        for (int reg = 0; reg < 4; ++reg) {
            float s2 = 0.f;
#pragma unroll
            for (int nt = 0; nt < NT; ++nt) {
                float v = acc[nt][reg] + b_s[nt * 16 + c];
                acc[nt][reg] = v;
                s2 += v * v;
            }
            s2 += __shfl_xor(s2, 1); s2 += __shfl_xor(s2, 2);
            s2 += __shfl_xor(s2, 4); s2 += __shfl_xor(s2, 8);
            rs[reg] = 1.0f / fmaxf(sqrtf(s2), 1e-12f);
        }

#pragma unroll
        for (int nt = 0; nt < NT; ++nt)
#pragma unroll
            for (int reg = 0; reg < 4; ++reg) {
                int nn  = nbw + quad * 4 + reg;
                int col = nt * 16 + c;
                if (nn < N_NODES && col < COUT) {
                    float v = acc[nt][reg] * rs[reg];
                    if (RELU) v = fmaxf(v, 0.0f);
                    if (FINAL) {
                        if (isbf) ((__hip_bfloat16*)dout)[(size_t)nn * COUT + col] = __float2bfloat16(v);
                        else      ((float*)dout)[(size_t)nn * COUT + col] = v;
                    } else {
                        h_out[(size_t)nn * H_DIM + col] = __float2bfloat16(v);
                    }
                }
            }
    }
}

extern "C" void kernel_launch(void* const* d_in, const int* in_sizes, int n_in,
                              void* d_out, int out_size, void* d_ws, size_t ws_size,
                              hipStream_t stream)
{
    const void* x    = d_in[0];
    const void* ei   = d_in[1];
    const void* ew   = d_in[2];
    const void* embW = d_in[3];
    const void* embB = d_in[4];
    const void* Wl1 = d_in[5];  const void* bl1 = d_in[6];  const void* Wr1 = d_in[7];
    const void* Wl2 = d_in[8];  const void* bl2 = d_in[9];  const void* Wr2 = d_in[10];
    const void* Wl3 = d_in[11]; const void* bl3 = d_in[12]; const void* Wr3 = d_in[13];
    const void* Wl4 = d_in[14]; const void* bl4 = d_in[15]; const void* Wr4 = d_in[16];
    (void)in_sizes; (void)n_in; (void)out_size; (void)ws_size;

    char* ws = (char*)d_ws;
    size_t off = 0;
    auto alloc = [&](size_t bytes) -> void* {
        void* p = ws + off;
        off += (bytes + 255) & ~(size_t)255;
        return p;
    };
    // temp (edge staging, 25.6 MB) is dead after csr_build; hA/hB alias it.
    uint2* temp = (uint2*)alloc((size_t)N_EDGES * sizeof(uint2));
    __hip_bfloat16* hA = (__hip_bfloat16*)temp;
    __hip_bfloat16* hB = (__hip_bfloat16*)((char*)temp + (size_t)N_NODES * H_DIM * 2);
    unsigned int* csr_pk = (unsigned int*)alloc((size_t)N_EDGES * sizeof(unsigned int));
    __hip_bfloat16* mn = (__hip_bfloat16*)alloc((size_t)N_NODES * H_DIM * 2);  // 12.8 MB
    int*   pcnt    = (int*)  alloc((N_BKT)     * sizeof(int));
    int*   pbase   = (int*)  alloc((N_BKT + 1) * sizeof(int));
    int*   pcursor = (int*)  alloc((N_BKT)     * sizeof(int));
    int*   deg     = (int*)  alloc((size_t)N_NODES * sizeof(int));
    int*   row_st  = (int*)  alloc((size_t)N_NODES * sizeof(int));
    float* inv_deg = (float*)alloc((size_t)N_NODES * sizeof(float));
    int*   flags   = (int*)  alloc(256);

    const int NBr = (N_EDGES + EPB - 1) / EPB;   // 391 radix blocks

    detect_kernel<<<1, 64, 0, stream>>>(ei, x, flags);
    zero98<<<1, 128, 0, stream>>>(pcnt);
    radix_count<<<NBr, 1024, 0, stream>>>(ei, pcnt, flags);
    scan98<<<1, 128, 0, stream>>>(pcnt, pbase, pcursor);
    radix_scatter<<<NBr, 1024, 0, stream>>>(ei, ew, pcursor, temp, flags);
    csr_build<<<N_BKT, NPB, 0, stream>>>(temp, pbase, csr_pk, deg, row_st, inv_deg);

    embed_mfma<<<512, 256, 0, stream>>>(x, embW, embB, hA, flags);

    gather_mean<true><<<2048, 256, 0, stream>>>(hA, csr_pk, row_st, deg, inv_deg, mn);
    transform_mfma<H_DIM, true, false><<<512, 256, 0, stream>>>(
        mn, hA, Wl1, bl1, Wr1, hB, flags, d_out);
    gather_mean<true><<<2048, 256, 0, stream>>>(hB, csr_pk, row_st, deg, inv_deg, mn);
    transform_mfma<H_DIM, true, false><<<512, 256, 0, stream>>>(
        mn, hB, Wl2, bl2, Wr2, hA, flags, d_out);
    gather_mean<true><<<2048, 256, 0, stream>>>(hA, csr_pk, row_st, deg, inv_deg, mn);
    transform_mfma<H_DIM, true, false><<<512, 256, 0, stream>>>(
        mn, hA, Wl3, bl3, Wr3, hB, flags, d_out);
    gather_mean<false><<<2048, 256, 0, stream>>>(hB, csr_pk, row_st, deg, inv_deg, mn);
    transform_mfma<C_NUM, false, true><<<512, 256, 0, stream>>>(
        mn, hB, Wl4, bl4, Wr4, nullptr, flags, d_out);
}